// Round 19
// baseline (850.025 us; speedup 1.0000x reference)
//
#include <hip/hip_runtime.h>

#define BATCH   16384
#define IN_DIM  1024
#define OUT_DIM 4096
#define K_TOP   409

typedef _Float16 half8  __attribute__((ext_vector_type(8)));
typedef _Float16 half4v __attribute__((ext_vector_type(4)));
typedef float    f32x4  __attribute__((ext_vector_type(4)));

// workspace layout: [0..4) flag | [256 ..) x_h (16M f16) | then w_h (4M f16)
#define WS_XH_OFF   256
#define WS_WH_OFF   (WS_XH_OFF + (size_t)BATCH * IN_DIM * 2)
#define WS_NEEDED   (WS_WH_OFF + (size_t)OUT_DIM * IN_DIM * 2)

// ---------------------------------------------------------------- kernel A
__global__ __launch_bounds__(256)
void k_hasneg(const float* __restrict__ x, int n, int* __restrict__ flag) {
    const int stride = gridDim.x * blockDim.x;
    bool neg = false;
    for (int i = blockIdx.x * blockDim.x + threadIdx.x; i < n; i += stride)
        neg |= (x[i] < 0.0f);
    unsigned long long b = __ballot(neg);
    if (b != 0ULL && (threadIdx.x & 63) == 0)
        atomicOr(flag, 1);
}

// ---------------------------------------------------------------- kernel A2
__global__ __launch_bounds__(256)
void k_cvt(const float* __restrict__ x, const float* __restrict__ w,
           _Float16* __restrict__ xh, _Float16* __restrict__ wh,
           const int* __restrict__ flag) {
    const bool bipolar = (*flag == 0);
    const int stride = gridDim.x * blockDim.x;
    const int nx4 = BATCH * IN_DIM / 4;
    const int nw4 = OUT_DIM * IN_DIM / 4;
    for (int i = blockIdx.x * blockDim.x + threadIdx.x; i < nx4; i += stride) {
        float4 v = ((const float4*)x)[i];
        if (bipolar) {
            v.x = (v.x - 0.5f) * 2.0f; v.y = (v.y - 0.5f) * 2.0f;
            v.z = (v.z - 0.5f) * 2.0f; v.w = (v.w - 0.5f) * 2.0f;
        }
        ((half4v*)xh)[i] = half4v{ (_Float16)v.x, (_Float16)v.y,
                                   (_Float16)v.z, (_Float16)v.w };
    }
    for (int i = blockIdx.x * blockDim.x + threadIdx.x; i < nw4; i += stride) {
        float4 u = ((const float4*)w)[i];
        ((half4v*)wh)[i] = half4v{ (_Float16)u.x, (_Float16)u.y,
                                   (_Float16)u.z, (_Float16)u.w };
    }
}

// ---------------------------------------------------------------- kernel B
// (unchanged from r16: global_load_lds w16, pre-swizzled source, 0 conflicts)
__global__ __launch_bounds__(256)
void k_gemm16(const _Float16* __restrict__ xh, const _Float16* __restrict__ wh,
              float* __restrict__ out) {
    __shared__ _Float16 Ah[128 * 64];
    __shared__ _Float16 Bh[128 * 64];
    const int tid = threadIdx.x;
    const int bm = blockIdx.x, bn = blockIdx.y;
    const int lane = tid & 63;
    const int wv = tid >> 6;
    const int wm = wv >> 1, wn = wv & 1;
    const int lr = lane & 15, lk = lane >> 4;

    const int srow = (lane >> 3);
    const int sslot = (lane & 7) ^ srow;
    f32x4 acc[4][4] = {};

    const _Float16* aS[4]; const _Float16* bS[4];
    _Float16* aD[4]; _Float16* bD[4];
    #pragma unroll
    for (int i = 0; i < 4; ++i) {
        const int rb = i * 32 + wv * 8;
        aS[i] = xh + (size_t)(bm * 128 + rb + srow) * IN_DIM + sslot * 8;
        bS[i] = wh + (size_t)(bn * 128 + rb + srow) * IN_DIM + sslot * 8;
        aD[i] = &Ah[rb * 64];
        bD[i] = &Bh[rb * 64];
    }

    #pragma unroll 1
    for (int kt = 0; kt < IN_DIM; kt += 64) {
        __syncthreads();
        #pragma unroll
        for (int i = 0; i < 4; ++i) {
            __builtin_amdgcn_global_load_lds((const __attribute__((address_space(1))) void*)(aS[i] + kt), (__attribute__((address_space(3))) void*)aD[i], 16, 0, 0);
            __builtin_amdgcn_global_load_lds((const __attribute__((address_space(1))) void*)(bS[i] + kt), (__attribute__((address_space(3))) void*)bD[i], 16, 0, 0);
        }
        __syncthreads();
        #pragma unroll
        for (int h = 0; h < 2; ++h) {
            half8 af[4], bf[4];
            #pragma unroll
            for (int i = 0; i < 4; ++i) {
                const int ra = wm * 64 + i * 16 + lr;
                const int sa = (h * 4 + lk) ^ (ra & 7);
                af[i] = *(const half8*)&Ah[ra * 64 + (sa << 3)];
                const int rb = wn * 64 + i * 16 + lr;
                const int sb = (h * 4 + lk) ^ (rb & 7);
                bf[i] = *(const half8*)&Bh[rb * 64 + (sb << 3)];
            }
            #pragma unroll
            for (int i = 0; i < 4; ++i)
                #pragma unroll
                for (int j = 0; j < 4; ++j)
                    acc[i][j] = __builtin_amdgcn_mfma_f32_16x16x32_f16(
                        af[i], bf[j], acc[i][j], 0, 0, 0);
        }
    }
    #pragma unroll
    for (int i = 0; i < 4; ++i)
        #pragma unroll
        for (int j = 0; j < 4; ++j)
            #pragma unroll
            for (int q = 0; q < 4; ++q) {
                const int row = bm * 128 + wm * 64 + i * 16 + lk * 4 + q;
                const int col = bn * 128 + wn * 64 + j * 16 + lr;
                out[(size_t)row * OUT_DIM + col] = acc[i][j][q];
            }
}

// ---------------------------------------------------------------- kernel B'
__global__ __launch_bounds__(256)
void k_gemm_fb(const float* __restrict__ x, const float* __restrict__ w,
               float* __restrict__ out, const int* __restrict__ flag) {
    __shared__ _Float16 Ah[128 * 64];
    __shared__ _Float16 Bh[128 * 64];
    const int tid = threadIdx.x;
    const int bm = blockIdx.x, bn = blockIdx.y;
    const bool bipolar = (*flag == 0);
    const int lane = tid & 63;
    const int wv = tid >> 6;
    const int wm = wv >> 1, wn = wv & 1;
    const int lr = lane & 15, lk = lane >> 4;
    const int sr = tid >> 1;
    const int sc = (tid & 1) * 32;
    const float* xr = x + (size_t)(bm * 128 + sr) * IN_DIM;
    const float* wrow = w + (size_t)(bn * 128 + sr) * IN_DIM;
    f32x4 acc[4][4] = {};
    #pragma unroll 1
    for (int kt = 0; kt < IN_DIM; kt += 64) {
        __syncthreads();
        #pragma unroll
        for (int i = 0; i < 8; ++i) {
            const int c = sc + i * 4;
            const int off = sr * 64 + ((((c >> 3) ^ (sr & 7))) << 3) + (c & 7);
            float4 v = *(const float4*)&xr[kt + c];
            if (bipolar) {
                v.x = (v.x - 0.5f) * 2.0f; v.y = (v.y - 0.5f) * 2.0f;
                v.z = (v.z - 0.5f) * 2.0f; v.w = (v.w - 0.5f) * 2.0f;
            }
            *(half4v*)&Ah[off] = half4v{ (_Float16)v.x, (_Float16)v.y,
                                         (_Float16)v.z, (_Float16)v.w };
            float4 u = *(const float4*)&wrow[kt + c];
            *(half4v*)&Bh[off] = half4v{ (_Float16)u.x, (_Float16)u.y,
                                         (_Float16)u.z, (_Float16)u.w };
        }
        __syncthreads();
        #pragma unroll
        for (int h = 0; h < 2; ++h) {
            half8 af[4], bf[4];
            #pragma unroll
            for (int i = 0; i < 4; ++i) {
                const int ra = wm * 64 + i * 16 + lr;
                const int sa = (h * 4 + lk) ^ (ra & 7);
                af[i] = *(const half8*)&Ah[ra * 64 + (sa << 3)];
                const int rb = wn * 64 + i * 16 + lr;
                const int sb = (h * 4 + lk) ^ (rb & 7);
                bf[i] = *(const half8*)&Bh[rb * 64 + (sb << 3)];
            }
            #pragma unroll
            for (int i = 0; i < 4; ++i)
                #pragma unroll
                for (int j = 0; j < 4; ++j)
                    acc[i][j] = __builtin_amdgcn_mfma_f32_16x16x32_f16(
                        af[i], bf[j], acc[i][j], 0, 0, 0);
        }
    }
    #pragma unroll
    for (int i = 0; i < 4; ++i)
        #pragma unroll
        for (int j = 0; j < 4; ++j)
            #pragma unroll
            for (int q = 0; q < 4; ++q) {
                const int row = bm * 128 + wm * 64 + i * 16 + lk * 4 + q;
                const int col = bn * 128 + wn * 64 + j * 16 + lr;
                out[(size_t)row * OUT_DIM + col] = acc[i][j][q];
            }
}

// ---------------------------------------------------------------- kernel C
// 4 rows/block, one row per wave, row register-resident — but with the
// r17-PROVEN synchronization discipline: __syncthreads() at every
// cross-phase LDS dependency (barriers are block-wide; need-region made
// uniform via __syncthreads_or), LDS-atomic slot compaction + linear-search
// matching in the encode pass (no ballot-replay coupling). Window math,
// replica chain (exact r13: single acc, ascending-k __fmaf_rn), and rank
// semantics (tie-inclusive) identical to the proven r17 kernel.
__global__ __launch_bounds__(256)
void k_select(float* __restrict__ po, const float* __restrict__ x,
              const float* __restrict__ w, const int* __restrict__ flag) {
    __shared__ unsigned int bins[4][256];    // 4 KB
    __shared__ float xs[4][IN_DIM];          // 16 KB
    __shared__ int bl_idx[4][64];
    __shared__ float bl_np[4][64];
    __shared__ unsigned char bl_sel[4][64];
    __shared__ int s_bstar[4];
    __shared__ unsigned int s_slot[4];

    const int tid = threadIdx.x;
    const int lane = tid & 63;
    const int wv = tid >> 6;
    const int row = blockIdx.x * 4 + wv;
    float* prow = po + (size_t)row * OUT_DIM;
    const float4* prow4 = (const float4*)prow;

    // ---- load row into registers; wave max via shfl
    float4 r[16];
    float vmax = -1e30f;
    #pragma unroll
    for (int u = 0; u < 16; ++u) {
        r[u] = prow4[lane + 64 * u];
        vmax = fmaxf(vmax, fmaxf(fmaxf(r[u].x, r[u].y), fmaxf(r[u].z, r[u].w)));
    }
    #pragma unroll
    for (int off = 32; off > 0; off >>= 1)
        vmax = fmaxf(vmax, __shfl_xor(vmax, off));
    vmax = fmaxf(vmax, 1e-6f);
    const float scale = 256.0f / vmax;
    const float invscale = vmax * (1.0f / 256.0f);

    #pragma unroll
    for (int u = 0; u < 4; ++u) bins[wv][lane + 64 * u] = 0;
    if (lane == 0) { s_bstar[wv] = 0; s_slot[wv] = 0; }
    __syncthreads();                          // init visible

    // ---- histogram (positives)
    #pragma unroll
    for (int u = 0; u < 16; ++u) {
        #pragma unroll
        for (int e = 0; e < 4; ++e) {
            float f = (e == 0) ? r[u].x : (e == 1) ? r[u].y
                    : (e == 2) ? r[u].z : r[u].w;
            if (f > 0.0f) {
                int b = (int)(f * scale);
                if (b > 255) b = 255;
                atomicAdd(&bins[wv][b], 1u);
            }
        }
    }
    __syncthreads();                          // histogram visible

    // ---- descending shfl-scan over 64 groups of 4 bins
    const int g = 63 - lane;
    const unsigned int c = bins[wv][4 * g] + bins[wv][4 * g + 1]
                         + bins[wv][4 * g + 2] + bins[wv][4 * g + 3];
    unsigned int sc = c;
    #pragma unroll
    for (int off = 1; off < 64; off <<= 1) {
        unsigned int t2 = __shfl_up(sc, off);
        if (lane >= off) sc += t2;
    }
    if ((int)sc >= K_TOP && (int)(sc - c) < K_TOP) {
        int cum = (int)(sc - c);
        int bstar = 4 * g;
        for (int bi = 4 * g + 3; bi >= 4 * g; --bi) {
            cum += (int)bins[wv][bi];
            if (cum >= K_TOP) { bstar = bi; break; }
        }
        s_bstar[wv] = bstar;
    }
    __syncthreads();                          // bstar visible
    const int bstar = s_bstar[wv];
    const float delta = 8e-3f;
    const float thi = (float)(bstar + 1) * invscale + delta;
    const float tlo = (float)bstar * invscale - delta;

    // ---- classify: counts via ballot, slots via LDS atomic counter
    int hi = 0, nb = 0;
    #pragma unroll
    for (int u = 0; u < 16; ++u) {
        #pragma unroll
        for (int e = 0; e < 4; ++e) {
            float f = (e == 0) ? r[u].x : (e == 1) ? r[u].y
                    : (e == 2) ? r[u].z : r[u].w;
            bool isbl = (f <= thi) && (f >= tlo);
            hi += (int)__popcll(__ballot(f > thi));
            nb += (int)__popcll(__ballot(isbl));
            if (isbl) {
                unsigned int p = atomicAdd(&s_slot[wv], 1u);
                if (p < 64) bl_idx[wv][p] = (lane + 64 * u) * 4 + e;
            }
        }
    }
    int nbc = nb > 64 ? 64 : nb;
    int krem = K_TOP - hi; if (krem > nb) krem = nb; if (krem < 0) krem = 0;
    const bool need = (nb != krem);

    const int anyneed = __syncthreads_or(need ? 1 : 0);   // also fences bl_idx
    if (anyneed) {
        if (need) {
            const bool bipolar = (*flag == 0);
            const float4* xr4 = (const float4*)(x + (size_t)row * IN_DIM);
            #pragma unroll
            for (int u = 0; u < 4; ++u) {
                float4 xv = xr4[lane + 64 * u];
                if (bipolar) {
                    xv.x = __fmul_rn(__fadd_rn(xv.x, -0.5f), 2.0f);
                    xv.y = __fmul_rn(__fadd_rn(xv.y, -0.5f), 2.0f);
                    xv.z = __fmul_rn(__fadd_rn(xv.z, -0.5f), 2.0f);
                    xv.w = __fmul_rn(__fadd_rn(xv.w, -0.5f), 2.0f);
                }
                ((float4*)xs[wv])[lane + 64 * u] = xv;
            }
        }
        __syncthreads();                      // xs visible
        if (need && lane < nbc) {
            // EXACT reference chain (bitwise r13): single acc, ascending k,
            // fused FMA, 2-stage register double-buffered loads.
            const float4* wr4 = (const float4*)(w + (size_t)bl_idx[wv][lane] * IN_DIM);
            const float4* xs4 = (const float4*)xs[wv];
            float4 bA[8], bB[8];
            #pragma unroll
            for (int u = 0; u < 8; ++u) bA[u] = wr4[u];
            float p = 0.0f;
            #pragma unroll 1
            for (int gg = 0; gg < 16; ++gg) {
                #pragma unroll
                for (int u = 0; u < 8; ++u) bB[u] = wr4[(2 * gg + 1) * 8 + u];
                #pragma unroll
                for (int u = 0; u < 8; ++u) {
                    float4 xv = xs4[(2 * gg) * 8 + u];
                    p = __fmaf_rn(xv.x, bA[u].x, p);
                    p = __fmaf_rn(xv.y, bA[u].y, p);
                    p = __fmaf_rn(xv.z, bA[u].z, p);
                    p = __fmaf_rn(xv.w, bA[u].w, p);
                }
                if (gg < 15) {
                    #pragma unroll
                    for (int u = 0; u < 8; ++u) bA[u] = wr4[(2 * gg + 2) * 8 + u];
                }
                #pragma unroll
                for (int u = 0; u < 8; ++u) {
                    float4 xv = xs4[(2 * gg + 1) * 8 + u];
                    p = __fmaf_rn(xv.x, bB[u].x, p);
                    p = __fmaf_rn(xv.y, bB[u].y, p);
                    p = __fmaf_rn(xv.z, bB[u].z, p);
                    p = __fmaf_rn(xv.w, bB[u].w, p);
                }
            }
            bl_np[wv][lane] = p;
        }
        __syncthreads();                      // bl_np visible
        if (need && lane < nbc) {
            // parallel rank, tie-inclusive: sel <=> #{np > mine} < krem
            const float v = bl_np[wv][lane];
            int gcount = 0;
            for (int l = 0; l < nbc; ++l) gcount += (bl_np[wv][l] > v);
            bl_sel[wv][lane] = (gcount < krem) ? 1 : 0;
        }
        __syncthreads();                      // bl_sel visible
    }

    // ---- encode: window elements matched by LINEAR SEARCH over bl_idx
    float nrm2 = 0.0f;
    #pragma unroll
    for (int u = 0; u < 16; ++u) {
        float4 o;
        #pragma unroll
        for (int e = 0; e < 4; ++e) {
            float f = (e == 0) ? r[u].x : (e == 1) ? r[u].y
                    : (e == 2) ? r[u].z : r[u].w;
            bool sel = (f > thi);
            float val = f;
            if (!sel && f >= tlo) {           // window element
                if (!need) sel = true;
                else {
                    const int j = (lane + 64 * u) * 4 + e;
                    sel = false;
                    for (int m = 0; m < nbc; ++m)
                        if (bl_idx[wv][m] == j) {
                            sel = (bl_sel[wv][m] != 0);
                            val = bl_np[wv][m];
                            break;
                        }
                }
            }
            float eo = (sel && val > 0.0f) ? val : 0.0f;
            if (e == 0) o.x = eo; else if (e == 1) o.y = eo;
            else if (e == 2) o.z = eo; else o.w = eo;
            nrm2 += eo * eo;
        }
        r[u] = o;
    }
    #pragma unroll
    for (int off = 32; off > 0; off >>= 1)
        nrm2 += __shfl_xor(nrm2, off);
    const float inv = 1.0f / fmaxf(sqrtf(nrm2), 1e-12f);
    #pragma unroll
    for (int u = 0; u < 16; ++u) {
        float4 e = r[u];
        e.x *= inv; e.y *= inv; e.z *= inv; e.w *= inv;
        ((float4*)prow)[lane + 64 * u] = e;
    }
}

// ---------------------------------------------------------------- launch
extern "C" void kernel_launch(void* const* d_in, const int* in_sizes, int n_in,
                              void* d_out, int out_size, void* d_ws, size_t ws_size,
                              hipStream_t stream) {
    const float* x = (const float*)d_in[0];
    const float* w = (const float*)d_in[1];
    float* out = (float*)d_out;
    int* flag = (int*)d_ws;

    hipMemsetAsync(flag, 0, sizeof(int), stream);
    k_hasneg<<<2048, 256, 0, stream>>>(x, BATCH * IN_DIM, flag);

    dim3 g(BATCH / 128, OUT_DIM / 128);
    if (ws_size >= WS_NEEDED) {
        _Float16* xh = (_Float16*)((char*)d_ws + WS_XH_OFF);
        _Float16* wh = (_Float16*)((char*)d_ws + WS_WH_OFF);
        k_cvt<<<2048, 256, 0, stream>>>(x, w, xh, wh, flag);
        k_gemm16<<<g, 256, 0, stream>>>(xh, wh, out);
    } else {
        k_gemm_fb<<<g, 256, 0, stream>>>(x, w, out, flag);
    }

    k_select<<<BATCH / 4, 256, 0, stream>>>(out, x, w, flag);
}